// Round 5
// baseline (3120.095 us; speedup 1.0000x reference)
//
#include <hip/hip_runtime.h>
#include <hip/hip_bf16.h>

// Problem constants: B=64, T=2048, IN_F=128, H1=OUT_F=64, 4H=256
#define BB 64
#define TT 2048
#define INF 128
#define HH 64
#define GG 256  // 4*H

__device__ __forceinline__ float sigm(float x) { return 1.0f / (1.0f + __expf(-x)); }
__device__ __forceinline__ float tanh_f(float x) {
  float e = __expf(2.0f * x);
  return 1.0f - 2.0f / (e + 1.0f);
}

// ---------------------------------------------------------------------------
// Kernel 1: xg1[m][n] = X[m,:].W_ih1[n,:] + b_ih1[n] + b_hh1[n]
// M=131072, N=256, K=128. 512 blocks x 256 threads. Thread t owns W row t
// (128 floats, source-unrolled constant indices). X staged per 64-row tile
// in LDS (32 KB); X values read as same-address float4 broadcasts
// (conflict-free). Output col t per thread -> coalesced stores.
// ---------------------------------------------------------------------------
#define XW1(I)                                                     \
  { float4 a = Wp[(I)];                                            \
    w[4*(I)] = a.x; w[4*(I)+1] = a.y; w[4*(I)+2] = a.z; w[4*(I)+3] = a.w; }
#define XW4(I) XW1(I) XW1((I)+1) XW1((I)+2) XW1((I)+3)
#define XWLOAD XW4(0) XW4(4) XW4(8) XW4(12) XW4(16) XW4(20) XW4(24) XW4(28)

#define XF1(Ki)                                                    \
  { float4 x4 = Xb[(Ki)];                                          \
    a0 = fmaf(x4.x, w[4*(Ki)],   a0); a1 = fmaf(x4.y, w[4*(Ki)+1], a1); \
    a2 = fmaf(x4.z, w[4*(Ki)+2], a2); a3 = fmaf(x4.w, w[4*(Ki)+3], a3); }
#define XF4(Ki) XF1(Ki) XF1((Ki)+1) XF1((Ki)+2) XF1((Ki)+3)
#define XF32 XF4(0) XF4(4) XF4(8) XF4(12) XF4(16) XF4(20) XF4(24) XF4(28)

__global__ __launch_bounds__(256, 1) void xgemm(const float* __restrict__ X,
                                                const float* __restrict__ W,
                                                const float* __restrict__ bi,
                                                const float* __restrict__ bh,
                                                float* __restrict__ XG) {
  __shared__ __align__(16) float Xs[64 * INF];  // 32 KB
  const int t = threadIdx.x;
  const long m0 = (long)blockIdx.x * 256;

  float w[INF];
  const float4* Wp = (const float4*)(W + (size_t)t * INF);
  XWLOAD
  const float bias = bi[t] + bh[t];

  for (int tile = 0; tile < 4; ++tile) {
    const float4* src = (const float4*)(X + (size_t)(m0 + tile * 64) * INF);
#pragma unroll
    for (int i = 0; i < 8; ++i) {
      int idx = t + i * 256;
      ((float4*)Xs)[idx] = src[idx];
    }
    __syncthreads();
    for (int r = 0; r < 64; ++r) {
      const float4* Xb = (const float4*)&Xs[r * INF];  // broadcast reads
      float a0 = bias, a1 = 0.f, a2 = 0.f, a3 = 0.f;
      XF32
      XG[(size_t)(m0 + tile * 64 + r) * GG + t] = (a0 + a1) + (a2 + a3);
    }
    __syncthreads();
  }
}

// ---------------------------------------------------------------------------
// Kernel 2: barrier-free wave-specialized LSTM pipeline (structure = r3/r4).
//   W0: layer-1 recurrence -> x2 ring.  W1: Wih2.x2 -> a2x ring.
//   W2: Whh2.h2 (before ring wait) + update + store.
// r5 change: h-broadcast via same-address LDS float4 reads (16/step) instead
// of 256 v_readlane per step per stage — halves VALU issue on every stage.
// ---------------------------------------------------------------------------
#define WL1(I)                                                                  \
  { float4 a = p[lane * 16 + (I)];                                              \
    wi[4*(I)] = a.x; wi[4*(I)+1] = a.y; wi[4*(I)+2] = a.z; wi[4*(I)+3] = a.w;   \
    float4 c = p[(64 + lane) * 16 + (I)];                                       \
    wf[4*(I)] = c.x; wf[4*(I)+1] = c.y; wf[4*(I)+2] = c.z; wf[4*(I)+3] = c.w;   \
    float4 d = p[(128 + lane) * 16 + (I)];                                      \
    wg[4*(I)] = d.x; wg[4*(I)+1] = d.y; wg[4*(I)+2] = d.z; wg[4*(I)+3] = d.w;   \
    float4 e = p[(192 + lane) * 16 + (I)];                                      \
    wo[4*(I)] = e.x; wo[4*(I)+1] = e.y; wo[4*(I)+2] = e.z; wo[4*(I)+3] = e.w; }
#define WL4(I) WL1(I) WL1((I)+1) WL1((I)+2) WL1((I)+3)
#define WLOAD WL4(0) WL4(4) WL4(8) WL4(12)

// One float4 broadcast read + 16 FMAs (4 k x 4 gates).
#define DL4(J, HB)                                                   \
  { float4 h4 = (HB)[(J)];                                           \
    ai = fmaf(h4.x, wi[4*(J)],   ai); af = fmaf(h4.x, wf[4*(J)],   af); \
    ag = fmaf(h4.x, wg[4*(J)],   ag); ao = fmaf(h4.x, wo[4*(J)],   ao); \
    ai = fmaf(h4.y, wi[4*(J)+1], ai); af = fmaf(h4.y, wf[4*(J)+1], af); \
    ag = fmaf(h4.y, wg[4*(J)+1], ag); ao = fmaf(h4.y, wo[4*(J)+1], ao); \
    ai = fmaf(h4.z, wi[4*(J)+2], ai); af = fmaf(h4.z, wf[4*(J)+2], af); \
    ag = fmaf(h4.z, wg[4*(J)+2], ag); ao = fmaf(h4.z, wo[4*(J)+2], ao); \
    ai = fmaf(h4.w, wi[4*(J)+3], ai); af = fmaf(h4.w, wf[4*(J)+3], af); \
    ag = fmaf(h4.w, wg[4*(J)+3], ag); ao = fmaf(h4.w, wo[4*(J)+3], ao); }
#define DOTL(HB) DL4(0,HB) DL4(1,HB) DL4(2,HB) DL4(3,HB) DL4(4,HB) DL4(5,HB) \
                 DL4(6,HB) DL4(7,HB) DL4(8,HB) DL4(9,HB) DL4(10,HB) DL4(11,HB) \
                 DL4(12,HB) DL4(13,HB) DL4(14,HB) DL4(15,HB)

__global__ __launch_bounds__(256, 1) void lstm2(const float* __restrict__ XG,
                                                const float* __restrict__ Whh1,
                                                const float* __restrict__ Wih2,
                                                const float* __restrict__ Whh2,
                                                const float* __restrict__ bi2,
                                                const float* __restrict__ bh2,
                                                const float* __restrict__ m1g,
                                                const float* __restrict__ m2g,
                                                float* __restrict__ out) {
  const int b = blockIdx.x;
  const int wid = threadIdx.x >> 6;
  const int lane = threadIdx.x & 63;

  __shared__ int f_w0, f_w1, f_w2;                  // steps completed per stage
  __shared__ __align__(16) float x2buf[4][HH];      // W0 -> W1 ring
  __shared__ __align__(16) float a2xbuf[4][GG];     // W1 -> W2 ring
  __shared__ __align__(16) float h1loc[HH];         // W0-private h1 copy
  __shared__ __align__(16) float h2loc[HH];         // W2-private h2 copy

  if (threadIdx.x == 0) { f_w0 = 0; f_w1 = 0; f_w2 = 0; }
  __syncthreads();  // one-time
  if (wid == 3) return;

#define WAIT_GE(flag, tgt)                                   \
  do {                                                       \
    while (*(volatile int*)&(flag) < (tgt)) {}               \
    asm volatile("" ::: "memory");                           \
  } while (0)
#define PUBLISH(flag, val)                                   \
  do {                                                       \
    asm volatile("s_waitcnt lgkmcnt(0)" ::: "memory");       \
    if (lane == 0) *(volatile int*)&(flag) = (val);          \
  } while (0)

  if (wid == 0) {
    // ---- stage 0: layer-1 recurrence ----
    float wi[HH], wf[HH], wg[HH], wo[HH];
    const float4* p = (const float4*)Whh1;
    WLOAD
    const float m1 = m1g[b * HH + lane];
    const float* xgp = XG + (size_t)b * TT * GG;
    h1loc[lane] = 0.f;  // own-wave buffer, no cross-wave sync needed

    float cur0 = xgp[lane], cur1 = xgp[64 + lane], cur2 = xgp[128 + lane], cur3 = xgp[192 + lane];
    float n10 = xgp[GG + lane], n11 = xgp[GG + 64 + lane], n12 = xgp[GG + 128 + lane], n13 = xgp[GG + 192 + lane];

    float c1 = 0.f;
    for (int s = 0; s < TT; ++s) {
      float n20 = 0.f, n21 = 0.f, n22 = 0.f, n23 = 0.f;
      if (s + 2 < TT) {
        const float* q = xgp + (size_t)(s + 2) * GG;
        n20 = q[lane]; n21 = q[64 + lane]; n22 = q[128 + lane]; n23 = q[192 + lane];
      }

      float ai = cur0, af = cur1, ag = cur2, ao = cur3;
      const float4* Hb = (const float4*)h1loc;   // broadcast reads
      DOTL(Hb)
      c1 = sigm(af) * c1 + sigm(ai) * tanh_f(ag);
      float h1 = sigm(ao) * tanh_f(c1);
      h1loc[lane] = h1;   // next step's broadcast source (same-wave ordering)

      WAIT_GE(f_w1, s - 3);                 // ring slot free?
      x2buf[s & 3][lane] = h1 * m1;
      PUBLISH(f_w0, s + 1);

      cur0 = n10; cur1 = n11; cur2 = n12; cur3 = n13;
      n10 = n20; n11 = n21; n12 = n22; n13 = n23;
    }
  } else if (wid == 1) {
    // ---- stage 1: layer-2 input dot ----
    float wi[HH], wf[HH], wg[HH], wo[HH];
    const float4* p = (const float4*)Wih2;
    WLOAD
    const float bi_i = bi2[lane] + bh2[lane];
    const float bi_f = bi2[64 + lane] + bh2[64 + lane];
    const float bi_g = bi2[128 + lane] + bh2[128 + lane];
    const float bi_o = bi2[192 + lane] + bh2[192 + lane];

    for (int s = 0; s < TT; ++s) {
      WAIT_GE(f_w0, s + 1);
      const float4* Hb = (const float4*)x2buf[s & 3];  // broadcast reads

      float ai = bi_i, af = bi_f, ag = bi_g, ao = bi_o;
      DOTL(Hb)
      WAIT_GE(f_w2, s - 3);                 // ring slot free?
      a2xbuf[s & 3][lane] = ai;
      a2xbuf[s & 3][64 + lane] = af;
      a2xbuf[s & 3][128 + lane] = ag;
      a2xbuf[s & 3][192 + lane] = ao;
      PUBLISH(f_w1, s + 1);
    }
  } else {
    // ---- stage 2: layer-2 recurrent dot + update + store ----
    float wi[HH], wf[HH], wg[HH], wo[HH];
    const float4* p = (const float4*)Whh2;
    WLOAD
    const float m2 = m2g[b * HH + lane];
    float* ob = out + (size_t)b * TT * HH;
    h2loc[lane] = 0.f;  // own-wave buffer

    float c2 = 0.f;
    for (int s = 0; s < TT; ++s) {
      // Whh2 . h2(s-1): no dependence on W1 -> compute BEFORE the ring wait.
      float ai = 0.f, af = 0.f, ag = 0.f, ao = 0.f;
      const float4* Hb = (const float4*)h2loc;   // broadcast reads
      DOTL(Hb)

      WAIT_GE(f_w1, s + 1);
      ai += a2xbuf[s & 3][lane];
      af += a2xbuf[s & 3][64 + lane];
      ag += a2xbuf[s & 3][128 + lane];
      ao += a2xbuf[s & 3][192 + lane];

      c2 = sigm(af) * c2 + sigm(ai) * tanh_f(ag);
      float h2 = sigm(ao) * tanh_f(c2);
      h2loc[lane] = h2;
      PUBLISH(f_w2, s + 1);
      ob[(size_t)s * HH + lane] = fmaxf(h2 * m2, 0.f);
    }
  }
#undef WAIT_GE
#undef PUBLISH
}

extern "C" void kernel_launch(void* const* d_in, const int* in_sizes, int n_in,
                              void* d_out, int out_size, void* d_ws, size_t ws_size,
                              hipStream_t stream) {
  (void)in_sizes; (void)n_in; (void)out_size; (void)ws_size;
  const float* x     = (const float*)d_in[0];
  const float* W_ih1 = (const float*)d_in[1];
  const float* W_hh1 = (const float*)d_in[2];
  const float* b_ih1 = (const float*)d_in[3];
  const float* b_hh1 = (const float*)d_in[4];
  const float* W_ih2 = (const float*)d_in[5];
  const float* W_hh2 = (const float*)d_in[6];
  const float* b_ih2 = (const float*)d_in[7];
  const float* b_hh2 = (const float*)d_in[8];
  const float* mask1 = (const float*)d_in[9];
  const float* mask2 = (const float*)d_in[10];
  float* out = (float*)d_out;

  float* xg1 = (float*)d_ws;  // B*T*4H fp32 = 134,217,728 bytes

  xgemm<<<dim3(BB * TT / 256), dim3(256), 0, stream>>>(x, W_ih1, b_ih1, b_hh1, xg1);
  lstm2<<<dim3(BB), dim3(256), 0, stream>>>(xg1, W_hh1, W_ih2, W_hh2, b_ih2, b_hh2,
                                            mask1, mask2, out);
}

// Round 6
// 2757.990 us; speedup vs baseline: 1.1313x; 1.1313x over previous
//
#include <hip/hip_runtime.h>
#include <hip/hip_bf16.h>

// Problem constants: B=64, T=2048, IN_F=128, H1=OUT_F=64, 4H=256
#define BB 64
#define TT 2048
#define INF 128
#define HH 64
#define GG 256  // 4*H

__device__ __forceinline__ float sigm(float x) { return 1.0f / (1.0f + __expf(-x)); }
__device__ __forceinline__ float tanh_f(float x) {
  float e = __expf(2.0f * x);
  return 1.0f - 2.0f / (e + 1.0f);
}

// ---- shared macro kit: literal-index loads so arrays stay in VGPRs --------
#define WLD1(A_, P_, I_)                                                     \
  { float4 q = (P_)[I_];                                                     \
    A_[4*(I_)] = q.x; A_[4*(I_)+1] = q.y; A_[4*(I_)+2] = q.z; A_[4*(I_)+3] = q.w; }
#define WLD16(A_, P_) WLD1(A_,P_,0) WLD1(A_,P_,1) WLD1(A_,P_,2) WLD1(A_,P_,3) \
  WLD1(A_,P_,4) WLD1(A_,P_,5) WLD1(A_,P_,6) WLD1(A_,P_,7) WLD1(A_,P_,8)      \
  WLD1(A_,P_,9) WLD1(A_,P_,10) WLD1(A_,P_,11) WLD1(A_,P_,12) WLD1(A_,P_,13)  \
  WLD1(A_,P_,14) WLD1(A_,P_,15)

// Batch all 16 broadcast LDS reads BEFORE any FMA (r5 lesson: interleaving
// exposes ~120cy LDS latency per read).
#define HRD1(I_) hb[I_] = Hb[I_];
#define HRD16 HRD1(0) HRD1(1) HRD1(2) HRD1(3) HRD1(4) HRD1(5) HRD1(6) HRD1(7) \
  HRD1(8) HRD1(9) HRD1(10) HRD1(11) HRD1(12) HRD1(13) HRD1(14) HRD1(15)

// 2-gate dot, 2 accumulator chains per gate (chain len 32 ~ issue-bound).
#define DG1(J_)                                                              \
  { float4 h4 = hb[J_];                                                      \
    aA0 = fmaf(h4.x, wa[4*(J_)],   aA0); aB0 = fmaf(h4.x, wb[4*(J_)],   aB0);\
    aA1 = fmaf(h4.y, wa[4*(J_)+1], aA1); aB1 = fmaf(h4.y, wb[4*(J_)+1], aB1);\
    aA0 = fmaf(h4.z, wa[4*(J_)+2], aA0); aB0 = fmaf(h4.z, wb[4*(J_)+2], aB0);\
    aA1 = fmaf(h4.w, wa[4*(J_)+3], aA1); aB1 = fmaf(h4.w, wb[4*(J_)+3], aB1); }
#define DG16 DG1(0) DG1(1) DG1(2) DG1(3) DG1(4) DG1(5) DG1(6) DG1(7)          \
  DG1(8) DG1(9) DG1(10) DG1(11) DG1(12) DG1(13) DG1(14) DG1(15)

// ---------------------------------------------------------------------------
// Kernel 1: xg1[m][n] = X[m,:].W_ih1[n,:] + b_ih1[n] + b_hh1[n]
// 512 blocks x 256 threads (2 blocks/CU). Thread t owns W row t in 128 VGPRs;
// X tile (64x128) in LDS; X read as broadcast float4s through two 8-f4
// buffers so >=8 reads are always in flight ahead of the FMAs.
// ---------------------------------------------------------------------------
#define XW1(I)                                                     \
  { float4 a = Wp[(I)];                                            \
    w[4*(I)] = a.x; w[4*(I)+1] = a.y; w[4*(I)+2] = a.z; w[4*(I)+3] = a.w; }
#define XW4(I) XW1(I) XW1((I)+1) XW1((I)+2) XW1((I)+3)
#define XWLOAD XW4(0) XW4(4) XW4(8) XW4(12) XW4(16) XW4(20) XW4(24) XW4(28)

#define GR1(B_, BASE_, I_) B_[I_] = Xb4[(BASE_) + (I_)];
#define GR8(B_, BASE_) GR1(B_,BASE_,0) GR1(B_,BASE_,1) GR1(B_,BASE_,2)       \
  GR1(B_,BASE_,3) GR1(B_,BASE_,4) GR1(B_,BASE_,5) GR1(B_,BASE_,6) GR1(B_,BASE_,7)
#define GF1(B_, WB_, I_)                                                     \
  { float4 h4 = B_[I_];                                                      \
    a0 = fmaf(h4.x, w[(WB_)+4*(I_)],   a0); a1 = fmaf(h4.y, w[(WB_)+4*(I_)+1], a1); \
    a2 = fmaf(h4.z, w[(WB_)+4*(I_)+2], a2); a3 = fmaf(h4.w, w[(WB_)+4*(I_)+3], a3); }
#define GF8(B_, WB_) GF1(B_,WB_,0) GF1(B_,WB_,1) GF1(B_,WB_,2) GF1(B_,WB_,3) \
  GF1(B_,WB_,4) GF1(B_,WB_,5) GF1(B_,WB_,6) GF1(B_,WB_,7)

__global__ __launch_bounds__(256, 1) void xgemm(const float* __restrict__ X,
                                                const float* __restrict__ W,
                                                const float* __restrict__ bi,
                                                const float* __restrict__ bh,
                                                float* __restrict__ XG) {
  __shared__ __align__(16) float Xs[64 * INF];  // 32 KB
  const int t = threadIdx.x;
  const long m0 = (long)blockIdx.x * 256;

  float w[INF];
  const float4* Wp = (const float4*)(W + (size_t)t * INF);
  XWLOAD
  const float bias = bi[t] + bh[t];

  for (int tile = 0; tile < 4; ++tile) {
    const float4* src = (const float4*)(X + (size_t)(m0 + tile * 64) * INF);
#pragma unroll
    for (int i = 0; i < 8; ++i) {
      int idx = t + i * 256;
      ((float4*)Xs)[idx] = src[idx];
    }
    __syncthreads();
    for (int r = 0; r < 64; ++r) {
      const float4* Xb4 = (const float4*)&Xs[r * INF];
      float4 ba[8], bb[8];
      float a0 = bias, a1 = 0.f, a2 = 0.f, a3 = 0.f;
      GR8(ba, 0) GR8(bb, 8)          // k 0..63 in flight
      GF8(ba, 0)                     // fma k 0..31
      GR8(ba, 16)                    // k 64..95 in flight
      GF8(bb, 32)                    // fma k 32..63
      GR8(bb, 24)                    // k 96..127 in flight
      GF8(ba, 64)                    // fma k 64..95
      GF8(bb, 96)                    // fma k 96..127
      XG[(size_t)(m0 + tile * 64 + r) * GG + t] = (a0 + a1) + (a2 + a3);
    }
    __syncthreads();
  }
}

// ---------------------------------------------------------------------------
// Kernel 2: barrier-free 6-wave gate-split LSTM pipeline. 64 blocks x 384.
// Per-wave weight footprint = 128 floats -> everything VGPR-resident.
//   A (wid2): L1 gates i,f dot + cell update -> h1loc, x2 ring   [SIMD2 alone]
//   B (wid0): L1 gates g,o dot -> gob1                           [SIMD0 w/ E]
//   C1(wid1): L2-input gates i,f dot -> a2x ring                 [SIMD1 w/ C2]
//   C2(wid5): L2-input gates g,o dot -> a2x ring
//   D (wid3): L2-recurrent i,f dot + update + relu store         [SIMD3 alone]
//   E (wid4): L2-recurrent g,o dot -> gob2
// Monotonic LDS flags; flag semantics: f_X = number of steps X completed.
// ---------------------------------------------------------------------------
__global__ __launch_bounds__(384, 1) void lstm2(const float* __restrict__ XG,
                                                const float* __restrict__ Whh1,
                                                const float* __restrict__ Wih2,
                                                const float* __restrict__ Whh2,
                                                const float* __restrict__ bi2,
                                                const float* __restrict__ bh2,
                                                const float* __restrict__ m1g,
                                                const float* __restrict__ m2g,
                                                float* __restrict__ out) {
  const int b = blockIdx.x;
  const int wid = threadIdx.x >> 6;
  const int lane = threadIdx.x & 63;

  __shared__ int fh1, fb, fc1, fc2, fh2, fe;
  __shared__ __align__(16) float h1loc[HH];
  __shared__ __align__(16) float h2loc[HH];
  __shared__ __align__(16) float x2buf[4][HH];
  __shared__ __align__(16) float gob1[4][2 * HH];   // B -> A (g at 0, o at 64)
  __shared__ __align__(16) float gob2[4][2 * HH];   // E -> D
  __shared__ __align__(16) float a2x[4][GG];        // C1/C2 -> D

  if (threadIdx.x == 0) { fh1 = 0; fb = 0; fc1 = 0; fc2 = 0; fh2 = 0; fe = 0; }
  if (threadIdx.x < HH) h1loc[threadIdx.x] = 0.f;
  else if (threadIdx.x < 2 * HH) h2loc[threadIdx.x - HH] = 0.f;
  __syncthreads();  // one-time

#define WAIT_GE(flag, tgt)                                   \
  do {                                                       \
    while (*(volatile int*)&(flag) < (tgt)) {}               \
    asm volatile("" ::: "memory");                           \
  } while (0)
#define PUBLISH(flag, val)                                   \
  do {                                                       \
    asm volatile("s_waitcnt lgkmcnt(0)" ::: "memory");       \
    if (lane == 0) *(volatile int*)&(flag) = (val);          \
  } while (0)

  if (wid == 2) {
    // ---- A: layer-1 gates i,f + update ----
    const float4* pa = (const float4*)(Whh1 + (size_t)lane * HH);
    const float4* pb = (const float4*)(Whh1 + (size_t)(64 + lane) * HH);
    float wa[HH], wb[HH];
    WLD16(wa, pa) WLD16(wb, pb)
    const float m1 = m1g[b * HH + lane];
    const float* xgp = XG + (size_t)b * TT * GG;

    float c1 = 0.f;
    float cur_i = xgp[lane], cur_f = xgp[64 + lane];
    float n1_i = xgp[GG + lane], n1_f = xgp[GG + 64 + lane];
    for (int s = 0; s < TT; ++s) {
      float n2_i = 0.f, n2_f = 0.f;
      if (s + 2 < TT) {
        const float* q = xgp + (size_t)(s + 2) * GG;
        n2_i = q[lane]; n2_f = q[64 + lane];
      }
      const float4* Hb = (const float4*)h1loc;   // own write from last iter
      float4 hb[16];
      HRD16
      float aA0 = cur_i, aA1 = 0.f, aB0 = cur_f, aB1 = 0.f;
      DG16
      WAIT_GE(fb, s + 1);
      float ag = gob1[s & 3][lane];
      float ao = gob1[s & 3][64 + lane];
      WAIT_GE(fc1, s - 3); WAIT_GE(fc2, s - 3);   // x2 ring slot free
      float ai = aA0 + aA1, af = aB0 + aB1;
      c1 = sigm(af) * c1 + sigm(ai) * tanh_f(ag);
      float h1 = sigm(ao) * tanh_f(c1);
      h1loc[lane] = h1;
      x2buf[s & 3][lane] = h1 * m1;
      PUBLISH(fh1, s + 1);
      cur_i = n1_i; cur_f = n1_f; n1_i = n2_i; n1_f = n2_f;
    }
  } else if (wid == 0) {
    // ---- B: layer-1 gates g,o dot ----
    const float4* pa = (const float4*)(Whh1 + (size_t)(128 + lane) * HH);
    const float4* pb = (const float4*)(Whh1 + (size_t)(192 + lane) * HH);
    float wa[HH], wb[HH];
    WLD16(wa, pa) WLD16(wb, pb)
    const float* xgp = XG + (size_t)b * TT * GG;

    float cur_g = xgp[128 + lane], cur_o = xgp[192 + lane];
    float n1_g = xgp[GG + 128 + lane], n1_o = xgp[GG + 192 + lane];
    for (int s = 0; s < TT; ++s) {
      float n2_g = 0.f, n2_o = 0.f;
      if (s + 2 < TT) {
        const float* q = xgp + (size_t)(s + 2) * GG;
        n2_g = q[128 + lane]; n2_o = q[192 + lane];
      }
      WAIT_GE(fh1, s);                            // h1loc == h1(s-1)
      const float4* Hb = (const float4*)h1loc;
      float4 hb[16];
      HRD16
      float aA0 = cur_g, aA1 = 0.f, aB0 = cur_o, aB1 = 0.f;
      DG16
      gob1[s & 3][lane] = aA0 + aA1;
      gob1[s & 3][64 + lane] = aB0 + aB1;
      PUBLISH(fb, s + 1);
      cur_g = n1_g; cur_o = n1_o; n1_g = n2_g; n1_o = n2_o;
    }
  } else if (wid == 1 || wid == 5) {
    // ---- C1/C2: layer-2 input dot (i,f) / (g,o) ----
    const int r0 = (wid == 1) ? 0 : 128;
    const float4* pa = (const float4*)(Wih2 + (size_t)(r0 + lane) * HH);
    const float4* pb = (const float4*)(Wih2 + (size_t)(r0 + 64 + lane) * HH);
    float wa[HH], wb[HH];
    WLD16(wa, pa) WLD16(wb, pb)
    const float bias_a = bi2[r0 + lane] + bh2[r0 + lane];
    const float bias_b = bi2[r0 + 64 + lane] + bh2[r0 + 64 + lane];

    for (int s = 0; s < TT; ++s) {
      WAIT_GE(fh1, s + 1);                        // x2(s) ready
      const float4* Hb = (const float4*)x2buf[s & 3];
      float4 hb[16];
      HRD16
      float aA0 = bias_a, aA1 = 0.f, aB0 = bias_b, aB1 = 0.f;
      DG16
      WAIT_GE(fh2, s - 3);                        // a2x slot free
      a2x[s & 3][r0 + lane] = aA0 + aA1;
      a2x[s & 3][r0 + 64 + lane] = aB0 + aB1;
      if (wid == 1) { PUBLISH(fc1, s + 1); } else { PUBLISH(fc2, s + 1); }
    }
  } else if (wid == 4) {
    // ---- E: layer-2 recurrent gates g,o dot ----
    const float4* pa = (const float4*)(Whh2 + (size_t)(128 + lane) * HH);
    const float4* pb = (const float4*)(Whh2 + (size_t)(192 + lane) * HH);
    float wa[HH], wb[HH];
    WLD16(wa, pa) WLD16(wb, pb)

    for (int s = 0; s < TT; ++s) {
      WAIT_GE(fh2, s);                            // h2loc == h2(s-1)
      const float4* Hb = (const float4*)h2loc;
      float4 hb[16];
      HRD16
      float aA0 = 0.f, aA1 = 0.f, aB0 = 0.f, aB1 = 0.f;
      DG16
      gob2[s & 3][lane] = aA0 + aA1;
      gob2[s & 3][64 + lane] = aB0 + aB1;
      PUBLISH(fe, s + 1);
    }
  } else {
    // ---- D: layer-2 recurrent gates i,f + update + store ----
    const float4* pa = (const float4*)(Whh2 + (size_t)lane * HH);
    const float4* pb = (const float4*)(Whh2 + (size_t)(64 + lane) * HH);
    float wa[HH], wb[HH];
    WLD16(wa, pa) WLD16(wb, pb)
    const float m2 = m2g[b * HH + lane];
    float* ob = out + (size_t)b * TT * HH;

    float c2 = 0.f;
    for (int s = 0; s < TT; ++s) {
      const float4* Hb = (const float4*)h2loc;    // own write from last iter
      float4 hb[16];
      HRD16
      float aA0 = 0.f, aA1 = 0.f, aB0 = 0.f, aB1 = 0.f;
      DG16
      WAIT_GE(fe, s + 1);
      WAIT_GE(fc1, s + 1); WAIT_GE(fc2, s + 1);
      float ai = aA0 + aA1 + a2x[s & 3][lane];
      float af = aB0 + aB1 + a2x[s & 3][64 + lane];
      float ag = gob2[s & 3][lane] + a2x[s & 3][128 + lane];
      float ao = gob2[s & 3][64 + lane] + a2x[s & 3][192 + lane];
      c2 = sigm(af) * c2 + sigm(ai) * tanh_f(ag);
      float h2 = sigm(ao) * tanh_f(c2);
      h2loc[lane] = h2;
      PUBLISH(fh2, s + 1);
      ob[(size_t)s * HH + lane] = fmaxf(h2 * m2, 0.f);  // off critical path
    }
  }
#undef WAIT_GE
#undef PUBLISH
}

extern "C" void kernel_launch(void* const* d_in, const int* in_sizes, int n_in,
                              void* d_out, int out_size, void* d_ws, size_t ws_size,
                              hipStream_t stream) {
  (void)in_sizes; (void)n_in; (void)out_size; (void)ws_size;
  const float* x     = (const float*)d_in[0];
  const float* W_ih1 = (const float*)d_in[1];
  const float* W_hh1 = (const float*)d_in[2];
  const float* b_ih1 = (const float*)d_in[3];
  const float* b_hh1 = (const float*)d_in[4];
  const float* W_ih2 = (const float*)d_in[5];
  const float* W_hh2 = (const float*)d_in[6];
  const float* b_ih2 = (const float*)d_in[7];
  const float* b_hh2 = (const float*)d_in[8];
  const float* mask1 = (const float*)d_in[9];
  const float* mask2 = (const float*)d_in[10];
  float* out = (float*)d_out;

  float* xg1 = (float*)d_ws;  // B*T*4H fp32 = 134,217,728 bytes

  xgemm<<<dim3(BB * TT / 256), dim3(256), 0, stream>>>(x, W_ih1, b_ih1, b_hh1, xg1);
  lstm2<<<dim3(BB), dim3(384), 0, stream>>>(xg1, W_hh1, W_ih2, W_hh2, b_ih2, b_hh2,
                                            mask1, mask2, out);
}

// Round 7
// 2579.029 us; speedup vs baseline: 1.2098x; 1.0694x over previous
//
#include <hip/hip_runtime.h>
#include <hip/hip_bf16.h>

// Problem constants: B=64, T=2048, IN_F=128, H1=OUT_F=64, 4H=256
#define BB 64
#define TT 2048
#define INF 128
#define HH 64
#define GG 256  // 4*H

__device__ __forceinline__ float sigm(float x) { return 1.0f / (1.0f + __expf(-x)); }
__device__ __forceinline__ float tanh_f(float x) {
  float e = __expf(2.0f * x);
  return 1.0f - 2.0f / (e + 1.0f);
}
// Wave-uniform broadcast of lane l's value via v_readlane (no LDS traffic).
#define RL(v, l) __uint_as_float(__builtin_amdgcn_readlane(__float_as_uint(v), (l)))

// Literal-index float4 weight loads (keep arrays promotable).
#define WLD1(A_, P_, I_)                                                     \
  { float4 q = (P_)[I_];                                                     \
    A_[4*(I_)] = q.x; A_[4*(I_)+1] = q.y; A_[4*(I_)+2] = q.z; A_[4*(I_)+3] = q.w; }
#define WLD16(A_, P_) WLD1(A_,P_,0) WLD1(A_,P_,1) WLD1(A_,P_,2) WLD1(A_,P_,3) \
  WLD1(A_,P_,4) WLD1(A_,P_,5) WLD1(A_,P_,6) WLD1(A_,P_,7) WLD1(A_,P_,8)      \
  WLD1(A_,P_,9) WLD1(A_,P_,10) WLD1(A_,P_,11) WLD1(A_,P_,12) WLD1(A_,P_,13)  \
  WLD1(A_,P_,14) WLD1(A_,P_,15)

// 2-gate dot step: broadcast h[k],h[k+1] from own lanes, 4 indep acc chains.
#define LD2(K)                                                               \
  { float h0_ = RL(hreg, (K)); float h1_ = RL(hreg, (K)+1);                  \
    aA0 = fmaf(h0_, wa[(K)],   aA0); aB0 = fmaf(h0_, wb[(K)],   aB0);        \
    aA1 = fmaf(h1_, wa[(K)+1], aA1); aB1 = fmaf(h1_, wb[(K)+1], aB1); }
#define LD8(K) LD2(K) LD2((K)+2) LD2((K)+4) LD2((K)+6)
#define DOT64 LD8(0) LD8(8) LD8(16) LD8(24) LD8(32) LD8(40) LD8(48) LD8(56)

// ---------------------------------------------------------------------------
// Kernel 1: xg1[m][n] = X[m,:].W_ih1[n,:] + b_ih1[n] + b_hh1[n]
// 512 blocks x 256 threads. Thread t owns W row t (128 VGPRs). x row is
// lane-distributed (float2/lane) and broadcast via readlane — ZERO LDS.
// All 4 waves process the same row m; lane l of wave w stores XG[m][64w+l].
// ---------------------------------------------------------------------------
#define XW1(I)                                                     \
  { float4 a = Wp[(I)];                                            \
    w[4*(I)] = a.x; w[4*(I)+1] = a.y; w[4*(I)+2] = a.z; w[4*(I)+3] = a.w; }
#define XW4(I) XW1(I) XW1((I)+1) XW1((I)+2) XW1((I)+3)
#define XWLOAD XW4(0) XW4(4) XW4(8) XW4(12) XW4(16) XW4(20) XW4(24) XW4(28)

#define XD2(L)                                                     \
  { float xa_ = RL(cx, (L)); float xb_ = RL(cy, (L));              \
    a0 = fmaf(xa_, w[2*(L)],   a0); a1 = fmaf(xb_, w[2*(L)+1], a1);\
    float xc_ = RL(cx, (L)+1); float xd_ = RL(cy, (L)+1);          \
    a2 = fmaf(xc_, w[2*(L)+2], a2); a3 = fmaf(xd_, w[2*(L)+3], a3); }
#define XD8(L) XD2(L) XD2((L)+2) XD2((L)+4) XD2((L)+6)
#define XDOT64 XD8(0) XD8(8) XD8(16) XD8(24) XD8(32) XD8(40) XD8(48) XD8(56)

__global__ __launch_bounds__(256, 2) void xgemm(const float* __restrict__ X,
                                                const float* __restrict__ W,
                                                const float* __restrict__ bi,
                                                const float* __restrict__ bh,
                                                float* __restrict__ XG) {
  const int t = threadIdx.x;            // 0..255: W gate-row
  const int lane = t & 63;
  const long m0 = (long)blockIdx.x * 256;

  float w[INF];
  const float4* Wp = (const float4*)(W + (size_t)t * INF);
  XWLOAD
  const float bias = bi[t] + bh[t];

  const float2* Xp = (const float2*)X;  // lane l holds k=2l,2l+1
  float2 cur = Xp[(size_t)m0 * 64 + lane];
  float2 nx1 = Xp[(size_t)(m0 + 1) * 64 + lane];

  for (int mi = 0; mi < 256; ++mi) {
    const long m = m0 + mi;
    float2 nx2 = (mi + 2 < 256) ? Xp[(size_t)(m + 2) * 64 + lane] : cur;

    const float cx = cur.x, cy = cur.y;
    float a0 = bias, a1 = 0.f, a2 = 0.f, a3 = 0.f;
    XDOT64
    XG[(size_t)m * GG + t] = (a0 + a1) + (a2 + a3);
    cur = nx1; nx1 = nx2;
  }
}

// ---------------------------------------------------------------------------
// Kernel 2: barrier-free 6-wave pipeline, symmetric replicated-state pairs,
// readlane dots (no LDS broadcasts). 64 blocks x 384 threads.
//   A(0): L1 gates i,f dot  <-> B(1): L1 gates g,o dot.  Both replicate
//         (c1,h1) per-lane; exchange 2 b32 each via depth-2 LDS; A also
//         publishes x2 = h1*mask1 to depth-4 ring.
//   D(2): L2-rec i,f <-> E(3): L2-rec g,o — same pattern on (c2,h2);
//         both read a2x from C/C'; D stores output.
//   C(4): L2-input i,f dot;  C'(5): L2-input g,o dot (x2 -> a2 rings).
// Weight footprint 128 floats/wave -> pure arch VGPRs (target of this round).
// ---------------------------------------------------------------------------
__global__ __launch_bounds__(384, 1) void lstm2(const float* __restrict__ XG,
                                                const float* __restrict__ Whh1,
                                                const float* __restrict__ Wih2,
                                                const float* __restrict__ Whh2,
                                                const float* __restrict__ bi2,
                                                const float* __restrict__ bh2,
                                                const float* __restrict__ m1g,
                                                const float* __restrict__ m2g,
                                                float* __restrict__ out) {
  const int b = blockIdx.x;
  const int wid = threadIdx.x >> 6;
  const int lane = threadIdx.x & 63;

  __shared__ int fAd, fBd, fh1, fc, fc2, fDd, fEd, fDu, fEu;
  __shared__ __align__(16) float d1if[2][2 * HH];   // A -> B  (i at 0, f at 64)
  __shared__ __align__(16) float d1go[2][2 * HH];   // B -> A  (g, o)
  __shared__ __align__(16) float d2if[2][2 * HH];   // D -> E
  __shared__ __align__(16) float d2go[2][2 * HH];   // E -> D
  __shared__ __align__(16) float x2buf[4][HH];      // A -> C,C'
  __shared__ __align__(16) float a2if[4][2 * HH];   // C -> D,E
  __shared__ __align__(16) float a2go[4][2 * HH];   // C' -> D,E

  if (threadIdx.x == 0) {
    fAd = 0; fBd = 0; fh1 = 0; fc = 0; fc2 = 0; fDd = 0; fEd = 0; fDu = 0; fEu = 0;
  }
  __syncthreads();  // one-time

#define WAIT_GE(flag, tgt)                                   \
  do {                                                       \
    while (*(volatile int*)&(flag) < (tgt)) {}               \
    asm volatile("" ::: "memory");                           \
  } while (0)
#define PUBLISH(flag, val)                                   \
  do {                                                       \
    asm volatile("s_waitcnt lgkmcnt(0)" ::: "memory");       \
    if (lane == 0) *(volatile int*)&(flag) = (val);          \
  } while (0)

  if (wid == 0) {
    // ---- A: L1 gates i,f + replicated update + x2 publish ----
    float wa[HH], wb[HH];
    { const float4* P1 = (const float4*)(Whh1 + (size_t)lane * HH);
      const float4* P2 = (const float4*)(Whh1 + (size_t)(64 + lane) * HH);
      WLD16(wa, P1) WLD16(wb, P2) }
    const float m1 = m1g[b * HH + lane];
    const float* xgp = XG + (size_t)b * TT * GG;

    float cur_i = xgp[lane], cur_f = xgp[64 + lane];
    float n1_i = xgp[GG + lane], n1_f = xgp[GG + 64 + lane];
    float hreg = 0.f, c1 = 0.f;
    for (int s = 0; s < TT; ++s) {
      float n2_i = 0.f, n2_f = 0.f;
      if (s + 2 < TT) {
        const float* q = xgp + (size_t)(s + 2) * GG;
        n2_i = q[lane]; n2_f = q[64 + lane];
      }
      float aA0 = cur_i, aA1 = 0.f, aB0 = cur_f, aB1 = 0.f;
      DOT64
      d1if[s & 1][lane] = aA0 + aA1;
      d1if[s & 1][64 + lane] = aB0 + aB1;
      PUBLISH(fAd, s + 1);
      WAIT_GE(fBd, s + 1);
      float ag = d1go[s & 1][lane], ao = d1go[s & 1][64 + lane];
      float ai = aA0 + aA1, af = aB0 + aB1;
      c1 = sigm(af) * c1 + sigm(ai) * tanh_f(ag);
      hreg = sigm(ao) * tanh_f(c1);
      WAIT_GE(fc, s - 2); WAIT_GE(fc2, s - 2);     // x2 slot free
      x2buf[s & 3][lane] = hreg * m1;
      PUBLISH(fh1, s + 1);
      cur_i = n1_i; cur_f = n1_f; n1_i = n2_i; n1_f = n2_f;
    }
  } else if (wid == 1) {
    // ---- B: L1 gates g,o + replicated update ----
    float wa[HH], wb[HH];
    { const float4* P1 = (const float4*)(Whh1 + (size_t)(128 + lane) * HH);
      const float4* P2 = (const float4*)(Whh1 + (size_t)(192 + lane) * HH);
      WLD16(wa, P1) WLD16(wb, P2) }
    const float* xgp = XG + (size_t)b * TT * GG;

    float cur_g = xgp[128 + lane], cur_o = xgp[192 + lane];
    float n1_g = xgp[GG + 128 + lane], n1_o = xgp[GG + 192 + lane];
    float hreg = 0.f, c1 = 0.f;
    for (int s = 0; s < TT; ++s) {
      float n2_g = 0.f, n2_o = 0.f;
      if (s + 2 < TT) {
        const float* q = xgp + (size_t)(s + 2) * GG;
        n2_g = q[128 + lane]; n2_o = q[192 + lane];
      }
      float aA0 = cur_g, aA1 = 0.f, aB0 = cur_o, aB1 = 0.f;
      DOT64
      d1go[s & 1][lane] = aA0 + aA1;
      d1go[s & 1][64 + lane] = aB0 + aB1;
      PUBLISH(fBd, s + 1);
      WAIT_GE(fAd, s + 1);
      float ai = d1if[s & 1][lane], af = d1if[s & 1][64 + lane];
      float ag = aA0 + aA1, ao = aB0 + aB1;
      c1 = sigm(af) * c1 + sigm(ai) * tanh_f(ag);
      hreg = sigm(ao) * tanh_f(c1);
      cur_g = n1_g; cur_o = n1_o; n1_g = n2_g; n1_o = n2_o;
    }
  } else if (wid == 2) {
    // ---- D: L2-rec i,f + replicated update + store ----
    float wa[HH], wb[HH];
    { const float4* P1 = (const float4*)(Whh2 + (size_t)lane * HH);
      const float4* P2 = (const float4*)(Whh2 + (size_t)(64 + lane) * HH);
      WLD16(wa, P1) WLD16(wb, P2) }
    const float m2 = m2g[b * HH + lane];
    float* ob = out + (size_t)b * TT * HH;

    float hreg = 0.f, c2 = 0.f;
    for (int s = 0; s < TT; ++s) {
      float aA0 = 0.f, aA1 = 0.f, aB0 = 0.f, aB1 = 0.f;
      DOT64
      d2if[s & 1][lane] = aA0 + aA1;
      d2if[s & 1][64 + lane] = aB0 + aB1;
      PUBLISH(fDd, s + 1);
      WAIT_GE(fEd, s + 1);
      float dg = d2go[s & 1][lane], do_ = d2go[s & 1][64 + lane];
      WAIT_GE(fc, s + 1); WAIT_GE(fc2, s + 1);
      float ai = aA0 + aA1 + a2if[s & 3][lane];
      float af = aB0 + aB1 + a2if[s & 3][64 + lane];
      float ag = dg + a2go[s & 3][lane];
      float ao = do_ + a2go[s & 3][64 + lane];
      c2 = sigm(af) * c2 + sigm(ai) * tanh_f(ag);
      hreg = sigm(ao) * tanh_f(c2);
      ob[(size_t)s * HH + lane] = fmaxf(hreg * m2, 0.f);
      PUBLISH(fDu, s + 1);
    }
  } else if (wid == 3) {
    // ---- E: L2-rec g,o + replicated update ----
    float wa[HH], wb[HH];
    { const float4* P1 = (const float4*)(Whh2 + (size_t)(128 + lane) * HH);
      const float4* P2 = (const float4*)(Whh2 + (size_t)(192 + lane) * HH);
      WLD16(wa, P1) WLD16(wb, P2) }

    float hreg = 0.f, c2 = 0.f;
    for (int s = 0; s < TT; ++s) {
      float aA0 = 0.f, aA1 = 0.f, aB0 = 0.f, aB1 = 0.f;
      DOT64
      d2go[s & 1][lane] = aA0 + aA1;
      d2go[s & 1][64 + lane] = aB0 + aB1;
      PUBLISH(fEd, s + 1);
      WAIT_GE(fDd, s + 1);
      float di = d2if[s & 1][lane], df = d2if[s & 1][64 + lane];
      WAIT_GE(fc, s + 1); WAIT_GE(fc2, s + 1);
      float ai = di + a2if[s & 3][lane];
      float af = df + a2if[s & 3][64 + lane];
      float ag = aA0 + aA1 + a2go[s & 3][lane];
      float ao = aB0 + aB1 + a2go[s & 3][64 + lane];
      c2 = sigm(af) * c2 + sigm(ai) * tanh_f(ag);
      hreg = sigm(ao) * tanh_f(c2);
      PUBLISH(fEu, s + 1);
    }
  } else if (wid == 4) {
    // ---- C: L2-input i,f dot ----
    float wa[HH], wb[HH];
    { const float4* P1 = (const float4*)(Wih2 + (size_t)lane * HH);
      const float4* P2 = (const float4*)(Wih2 + (size_t)(64 + lane) * HH);
      WLD16(wa, P1) WLD16(wb, P2) }
    const float bia = bi2[lane] + bh2[lane];
    const float bib = bi2[64 + lane] + bh2[64 + lane];

    for (int s = 0; s < TT; ++s) {
      WAIT_GE(fh1, s + 1);
      float hreg = x2buf[s & 3][lane];        // per-lane b32 read
      float aA0 = bia, aA1 = 0.f, aB0 = bib, aB1 = 0.f;
      DOT64
      WAIT_GE(fDu, s - 2); WAIT_GE(fEu, s - 2);   // a2 slot free
      a2if[s & 3][lane] = aA0 + aA1;
      a2if[s & 3][64 + lane] = aB0 + aB1;
      PUBLISH(fc, s + 1);
    }
  } else {
    // ---- C': L2-input g,o dot ----
    float wa[HH], wb[HH];
    { const float4* P1 = (const float4*)(Wih2 + (size_t)(128 + lane) * HH);
      const float4* P2 = (const float4*)(Wih2 + (size_t)(192 + lane) * HH);
      WLD16(wa, P1) WLD16(wb, P2) }
    const float bia = bi2[128 + lane] + bh2[128 + lane];
    const float bib = bi2[192 + lane] + bh2[192 + lane];

    for (int s = 0; s < TT; ++s) {
      WAIT_GE(fh1, s + 1);
      float hreg = x2buf[s & 3][lane];
      float aA0 = bia, aA1 = 0.f, aB0 = bib, aB1 = 0.f;
      DOT64
      WAIT_GE(fDu, s - 2); WAIT_GE(fEu, s - 2);
      a2go[s & 3][lane] = aA0 + aA1;
      a2go[s & 3][64 + lane] = aB0 + aB1;
      PUBLISH(fc2, s + 1);
    }
  }
#undef WAIT_GE
#undef PUBLISH
}

extern "C" void kernel_launch(void* const* d_in, const int* in_sizes, int n_in,
                              void* d_out, int out_size, void* d_ws, size_t ws_size,
                              hipStream_t stream) {
  (void)in_sizes; (void)n_in; (void)out_size; (void)ws_size;
  const float* x     = (const float*)d_in[0];
  const float* W_ih1 = (const float*)d_in[1];
  const float* W_hh1 = (const float*)d_in[2];
  const float* b_ih1 = (const float*)d_in[3];
  const float* b_hh1 = (const float*)d_in[4];
  const float* W_ih2 = (const float*)d_in[5];
  const float* W_hh2 = (const float*)d_in[6];
  const float* b_ih2 = (const float*)d_in[7];
  const float* b_hh2 = (const float*)d_in[8];
  const float* mask1 = (const float*)d_in[9];
  const float* mask2 = (const float*)d_in[10];
  float* out = (float*)d_out;

  float* xg1 = (float*)d_ws;  // B*T*4H fp32 = 134,217,728 bytes

  xgemm<<<dim3(BB * TT / 256), dim3(256), 0, stream>>>(x, W_ih1, b_ih1, b_hh1, xg1);
  lstm2<<<dim3(BB), dim3(384), 0, stream>>>(xg1, W_hh1, W_ih2, W_hh2, b_ih2, b_hh2,
                                            mask1, mask2, out);
}